// Round 4
// baseline (357.640 us; speedup 1.0000x reference)
//
#include <hip/hip_runtime.h>
#include <stdint.h>

// DTI WLS fit -> FA. Round 4 = round-3 pipeline, UNCHANGED output path,
// plus a deliberately duplicated (opaque, kept-alive, unused) noise block:
// a correctness-preserving probe that measures the marginal cost of the
// threefry/erfinv work inside this schedule, and pushes fa_kernel above the
// harness top-5 visibility cutoff to recover its rocprof counters.

__device__ __forceinline__ unsigned tf_rotl(unsigned x, int r) {
  return (x << r) | (x >> (32 - r));
}

// Threefry-2x32, 20 rounds, key (0, 42); returns SECOND output word.
__device__ __forceinline__ unsigned threefry_second(unsigned x0, unsigned x1) {
  const unsigned k0 = 0u, k1 = 42u;
  const unsigned k2 = 0x1BD11BDAu ^ k0 ^ k1;
  x0 += k0; x1 += k1;
#define TF_ROUND(r) { x0 += x1; x1 = tf_rotl(x1, r); x1 ^= x0; }
  TF_ROUND(13) TF_ROUND(15) TF_ROUND(26) TF_ROUND(6)
  x0 += k1; x1 += k2 + 1u;
  TF_ROUND(17) TF_ROUND(29) TF_ROUND(16) TF_ROUND(24)
  x0 += k2; x1 += k0 + 2u;
  TF_ROUND(13) TF_ROUND(15) TF_ROUND(26) TF_ROUND(6)
  x0 += k0; x1 += k1 + 3u;
  TF_ROUND(17) TF_ROUND(29) TF_ROUND(16) TF_ROUND(24)
  x0 += k1; x1 += k2 + 4u;
  TF_ROUND(13) TF_ROUND(15) TF_ROUND(26) TF_ROUND(6)
  x0 += k2; x1 += k0 + 5u;
#undef TF_ROUND
  (void)x0;
  return x1;
}

// XLA ErfInv32 (Giles), exact constants.
__device__ __forceinline__ float erfinv_xla(float x) {
  float w = -__logf(fmaf(-x, x, 1.0f));
  float p;
  if (w < 5.0f) {
    w = w - 2.5f;
    p = 2.81022636e-08f;
    p = fmaf(p, w, 3.43273939e-07f);
    p = fmaf(p, w, -3.5233877e-06f);
    p = fmaf(p, w, -4.39150654e-06f);
    p = fmaf(p, w, 0.00021858087f);
    p = fmaf(p, w, -0.00125372503f);
    p = fmaf(p, w, -0.00417768164f);
    p = fmaf(p, w, 0.246640727f);
    p = fmaf(p, w, 1.50140941f);
  } else {
    w = __builtin_sqrtf(w) - 3.0f;
    p = -0.000200214257f;
    p = fmaf(p, w, 0.000100950558f);
    p = fmaf(p, w, 0.00134934322f);
    p = fmaf(p, w, -0.00367342844f);
    p = fmaf(p, w, 0.00573950773f);
    p = fmaf(p, w, -0.0076224613f);
    p = fmaf(p, w, 0.00943887047f);
    p = fmaf(p, w, 1.00167406f);
    p = fmaf(p, w, 2.83297682f);
  }
  return p * x;
}

__device__ __forceinline__ float jax_normal_at(unsigned idx) {
  unsigned bits = threefry_second(0u, idx);   // counter hi = 0 (idx < 2^32)
  float f = __uint_as_float((bits >> 9) | 0x3F800000u);  // [1,2)
  float u = f - 1.0f;                                    // [0,1)
  const float lo = -0.99999994f;                          // nextafter(-1,0)
  float val = fmaf(u, 2.0f, lo);                          // (hi-lo) rounds to 2.0f
  val = fmaxf(lo, val);
  return 1.41421356237f * erfinv_xla(val);                // sqrt(2) in f32
}

#define NG 64

typedef __attribute__((address_space(1))) const void gvoid_t;
typedef __attribute__((address_space(3))) void lvoid_t;

#define VMWAIT(n) asm volatile("s_waitcnt vmcnt(" #n ")" ::: "memory")
#define CLOB()    asm volatile("" ::: "memory")

__global__ __launch_bounds__(256, 4) void fa_kernel(
    const float* __restrict__ dwi,
    const float* __restrict__ mask,
    const float* __restrict__ W,     // [7,64], rows 0..5 used
    const float* __restrict__ mdp,   // scalar min_diffusivity
    float* __restrict__ out,
    int nvox)
{
  // [wave][buf][slot]: 4 x 2 x 256 float4 = 32 KiB
  __shared__ float4 smem[4][2][256];

  const int t    = threadIdx.x;
  const int wid  = t >> 6;
  const int lane = t & 63;
  const int v    = blockIdx.x * 256 + t;
  const size_t wvox    = (size_t)blockIdx.x * 256 + (size_t)(wid * 64);
  const size_t totalF4 = (size_t)nvox * (NG / 4);

  const float md = mdp[0];

#define STAGE(c, b) do {                                                   \
    _Pragma("unroll")                                                      \
    for (int i = 0; i < 4; ++i) {                                          \
      int vl = i * 16 + (lane >> 2);                                       \
      int q  = (lane & 3) ^ ((vl >> 1) & 3);                               \
      size_t src = (wvox + (size_t)vl) * (NG / 4) + (c) * 4 + (size_t)q;   \
      if (src >= totalF4) src = 0;  /* tail clamp, data unused */          \
      __builtin_amdgcn_global_load_lds(                                    \
          (gvoid_t*)(dwi + src * 4),                                       \
          (lvoid_t*)(&smem[wid][(b)][i * 64]), 16, 0, 0);                  \
    }                                                                      \
    CLOB();                                                                \
  } while (0)

  float f0 = 0.f, f1 = 0.f, f2 = 0.f, f3 = 0.f, f4 = 0.f, f5 = 0.f;
  const int swz   = (lane >> 1) & 3;
  const int rbase = lane * 4;

#define MATVEC(c, b) do {                                                  \
    _Pragma("unroll")                                                      \
    for (int j = 0; j < 4; ++j) {                                          \
      float4 d = smem[wid][(b)][rbase + (j ^ swz)];                        \
      float xs[4];                                                         \
      xs[0] = __logf(fmaxf(d.x, md));                                      \
      xs[1] = __logf(fmaxf(d.y, md));                                      \
      xs[2] = __logf(fmaxf(d.z, md));                                      \
      xs[3] = __logf(fmaxf(d.w, md));                                      \
      _Pragma("unroll")                                                    \
      for (int k = 0; k < 4; ++k) {                                        \
        int jg = (c) * 16 + j * 4 + k;                                     \
        float x = xs[k];                                                   \
        f0 = fmaf(W[0 * NG + jg], x, f0);                                  \
        f1 = fmaf(W[1 * NG + jg], x, f1);                                  \
        f2 = fmaf(W[2 * NG + jg], x, f2);                                  \
        f3 = fmaf(W[3 * NG + jg], x, f3);                                  \
        f4 = fmaf(W[4 * NG + jg], x, f4);                                  \
        f5 = fmaf(W[5 * NG + jg], x, f5);                                  \
      }                                                                    \
    }                                                                      \
  } while (0)

  // ---- issue first two chunks (8 loads in flight) ----
  STAGE(0, 0);
  STAGE(1, 1);

  // ---- noise z[9]: pure ALU, hides staging HBM latency ----
  unsigned base = 9u * (unsigned)v;
  float z[9];
#pragma unroll
  for (int e = 0; e < 9; ++e) z[e] = jax_normal_at(base + (unsigned)e);

  // ---- MEASUREMENT PROBE: duplicated noise block (round-4 only) ----
  // Opaque input prevents CSE with z[e]; immediate keep-alive prevents DCE
  // (rule #17). One extra live VGPR at a time. Output path unaffected.
#pragma unroll
  for (int e = 0; e < 9; ++e) {
    unsigned idx2 = base + (unsigned)e;
    asm volatile("" : "+v"(idx2));          // opaque input
    float z2 = jax_normal_at(idx2);
    asm volatile("" :: "v"(z2));            // keep alive, then dead
  }

  // ---- pipelined consume: counted vmcnt, never drain to 0 mid-loop ----
  VMWAIT(4);          // S0 landed (S1 may be in flight)
  MATVEC(0, 0);
  STAGE(2, 0);        // safe: chunk0 values already consumed into regs
  VMWAIT(4);          // S1 landed (S2 in flight)
  MATVEC(1, 1);
  STAGE(3, 1);
  float mv = mask[v < nvox ? v : 0];  // pinned between CLOBs, counted below
  CLOB();
  VMWAIT(5);          // S2 landed (S3 + mask in flight)
  MATVEC(2, 0);
  VMWAIT(1);          // S3 landed (mask may be in flight)
  MATVEC(3, 1);

  // ---- tensor (LT_INDICES): [[f0,f1,f3],[f1,f2,f4],[f3,f4,f5]] + noise, symmetrized ----
  const float eps = 1e-6f;
  float a00 = f0 + eps * z[0];
  float a11 = f2 + eps * z[4];
  float a22 = f5 + eps * z[8];
  float a01 = ((f1 + eps * z[1]) + (f1 + eps * z[3])) * 0.5f;
  float a02 = ((f3 + eps * z[2]) + (f3 + eps * z[6])) * 0.5f;
  float a12 = ((f4 + eps * z[5]) + (f4 + eps * z[7])) * 0.5f;

  // ---- closed-form symmetric 3x3 eigenvalues (trigonometric method) ----
  float q = (a00 + a11 + a22) * (1.0f / 3.0f);
  float aa = a00 - q, bb = a11 - q, cc = a22 - q;
  float p2 = aa * aa + bb * bb + cc * cc +
             2.0f * (a01 * a01 + a02 * a02 + a12 * a12);
  float pp = __builtin_sqrtf(p2 * (1.0f / 6.0f));
  float invp = (pp > 0.0f) ? (1.0f / pp) : 0.0f;
  float b00 = aa * invp, b11 = bb * invp, b22 = cc * invp;
  float b01 = a01 * invp, b02 = a02 * invp, b12 = a12 * invp;
  float detB = b00 * (b11 * b22 - b12 * b12)
             - b01 * (b01 * b22 - b12 * b02)
             + b02 * (b01 * b12 - b11 * b02);
  float r = 0.5f * detB;
  r = fminf(1.0f, fmaxf(-1.0f, r));
  float phi = acosf(r) * (1.0f / 3.0f);
  float l0 = q + 2.0f * pp * cosf(phi);
  float l2 = q + 2.0f * pp * cosf(phi + 2.0943951023931953f); // +2pi/3
  float l1 = 3.0f * q - l0 - l2;

  // ---- clamp, FA ----
  l0 = fmaxf(l0, md);
  l1 = fmaxf(l1, md);
  l2 = fmaxf(l2, md);
  float d01 = l0 - l1, d12 = l1 - l2, d20 = l2 - l0;
  float num = 0.5f * (d01 * d01 + d12 * d12 + d20 * d20);
  float den = l0 * l0 + l1 * l1 + l2 * l2;  // >= 3*md^2 > 0
  float fa = __builtin_sqrtf(num / den);

  if (v < nvox) out[v] = fa * mv;
}

extern "C" void kernel_launch(void* const* d_in, const int* in_sizes, int n_in,
                              void* d_out, int out_size, void* d_ws, size_t ws_size,
                              hipStream_t stream) {
  const float* dwi  = (const float*)d_in[0];
  const float* mask = (const float*)d_in[1];
  const float* W    = (const float*)d_in[2];
  const float* mdp  = (const float*)d_in[3];
  float* out = (float*)d_out;
  int nvox = in_sizes[0] / NG;  // 1,000,000
  int grid = (nvox + 255) / 256;
  hipLaunchKernelGGL(fa_kernel, dim3(grid), dim3(256), 0, stream,
                     dwi, mask, W, mdp, out, nvox);
}

// Round 5
// 357.009 us; speedup vs baseline: 1.0018x; 1.0018x over previous
//
#include <hip/hip_runtime.h>
#include <stdint.h>

// DTI WLS fit -> FA. Round 5: Little's-law test.
// All prior structures (AoS-interleaved, LDS-staged sync, LDS-staged pipelined)
// land at the same ~150us fa / ~357us total, with VALU issue demonstrably idle
// (round-4 probe: +850 inst/voxel = +0.4us). Last candidate bottleneck for the
// kernel itself: memory-request concurrency. This version issues ALL 16 float4
// dwi loads (+mask) per thread BEFORE any consumption -> 256 outstanding 64B
// lines per wave (vs ~16 staged), 16 waves/CU. If fa was concurrency-pinned,
// this reaches the BW roofline (~50-80us). If total stays at 357+-1, the metric
// is floored by the harness's 1GB poison fill (152us @ 84% HBM peak) and the
// kernel is already fully hidden -> roofline.
//
// Noise replication (unchanged, exact): threefry2x32 key(0,42), 20 rounds,
// second word; normal = sqrt(2)*erfinv_XLA(u*2 + nextafter(-1,0)).

__device__ __forceinline__ unsigned tf_rotl(unsigned x, int r) {
  return (x << r) | (x >> (32 - r));
}

// Threefry-2x32, 20 rounds, key (0, 42); returns SECOND output word.
__device__ __forceinline__ unsigned threefry_second(unsigned x0, unsigned x1) {
  const unsigned k0 = 0u, k1 = 42u;
  const unsigned k2 = 0x1BD11BDAu ^ k0 ^ k1;
  x0 += k0; x1 += k1;
#define TF_ROUND(r) { x0 += x1; x1 = tf_rotl(x1, r); x1 ^= x0; }
  TF_ROUND(13) TF_ROUND(15) TF_ROUND(26) TF_ROUND(6)
  x0 += k1; x1 += k2 + 1u;
  TF_ROUND(17) TF_ROUND(29) TF_ROUND(16) TF_ROUND(24)
  x0 += k2; x1 += k0 + 2u;
  TF_ROUND(13) TF_ROUND(15) TF_ROUND(26) TF_ROUND(6)
  x0 += k0; x1 += k1 + 3u;
  TF_ROUND(17) TF_ROUND(29) TF_ROUND(16) TF_ROUND(24)
  x0 += k1; x1 += k2 + 4u;
  TF_ROUND(13) TF_ROUND(15) TF_ROUND(26) TF_ROUND(6)
  x0 += k2; x1 += k0 + 5u;
#undef TF_ROUND
  (void)x0;
  return x1;
}

// XLA ErfInv32 (Giles), exact constants.
__device__ __forceinline__ float erfinv_xla(float x) {
  float w = -__logf(fmaf(-x, x, 1.0f));
  float p;
  if (w < 5.0f) {
    w = w - 2.5f;
    p = 2.81022636e-08f;
    p = fmaf(p, w, 3.43273939e-07f);
    p = fmaf(p, w, -3.5233877e-06f);
    p = fmaf(p, w, -4.39150654e-06f);
    p = fmaf(p, w, 0.00021858087f);
    p = fmaf(p, w, -0.00125372503f);
    p = fmaf(p, w, -0.00417768164f);
    p = fmaf(p, w, 0.246640727f);
    p = fmaf(p, w, 1.50140941f);
  } else {
    w = __builtin_sqrtf(w) - 3.0f;
    p = -0.000200214257f;
    p = fmaf(p, w, 0.000100950558f);
    p = fmaf(p, w, 0.00134934322f);
    p = fmaf(p, w, -0.00367342844f);
    p = fmaf(p, w, 0.00573950773f);
    p = fmaf(p, w, -0.0076224613f);
    p = fmaf(p, w, 0.00943887047f);
    p = fmaf(p, w, 1.00167406f);
    p = fmaf(p, w, 2.83297682f);
  }
  return p * x;
}

__device__ __forceinline__ float jax_normal_at(unsigned idx) {
  unsigned bits = threefry_second(0u, idx);   // counter hi = 0 (idx < 2^32)
  float f = __uint_as_float((bits >> 9) | 0x3F800000u);  // [1,2)
  float u = f - 1.0f;                                    // [0,1)
  const float lo = -0.99999994f;                          // nextafter(-1,0)
  float val = fmaf(u, 2.0f, lo);                          // (hi-lo) rounds to 2.0f
  val = fmaxf(lo, val);
  return 1.41421356237f * erfinv_xla(val);                // sqrt(2) in f32
}

#define NG 64

__global__ __launch_bounds__(256, 4) void fa_kernel(
    const float* __restrict__ dwi,
    const float* __restrict__ mask,
    const float* __restrict__ W,     // [7,64], rows 0..5 used
    const float* __restrict__ mdp,   // scalar min_diffusivity
    float* __restrict__ out,
    int nvox)
{
  const int v  = blockIdx.x * 256 + threadIdx.x;
  const int vc = (v < nvox) ? v : 0;   // tail threads compute on voxel 0, no store

  const float md = mdp[0];

  // ---- full prefetch: ALL dwi loads issued before any consumption ----
  // 16 x float4 = statically-indexed register array (64 VGPR, no scratch).
  const float4* __restrict__ p =
      reinterpret_cast<const float4*>(dwi + (size_t)vc * NG);
  float4 xs16[16];
#pragma unroll
  for (int i = 0; i < 16; ++i) xs16[i] = p[i];
  float mv = mask[vc];
  asm volatile("" ::: "memory");   // pin: all 17 loads issued before first wait

  // ---- matvec: fit[i] = sum_j W[i][j] * log(max(dwi[v][j], md)) ----
  float f0 = 0.f, f1 = 0.f, f2 = 0.f, f3 = 0.f, f4 = 0.f, f5 = 0.f;
#pragma unroll
  for (int j4 = 0; j4 < 16; ++j4) {
    float4 d = xs16[j4];
    float xs[4];
    xs[0] = __logf(fmaxf(d.x, md));
    xs[1] = __logf(fmaxf(d.y, md));
    xs[2] = __logf(fmaxf(d.z, md));
    xs[3] = __logf(fmaxf(d.w, md));
#pragma unroll
    for (int k = 0; k < 4; ++k) {
      int j = j4 * 4 + k;
      float x = xs[k];
      f0 = fmaf(W[0 * NG + j], x, f0);
      f1 = fmaf(W[1 * NG + j], x, f1);
      f2 = fmaf(W[2 * NG + j], x, f2);
      f3 = fmaf(W[3 * NG + j], x, f3);
      f4 = fmaf(W[4 * NG + j], x, f4);
      f5 = fmaf(W[5 * NG + j], x, f5);
    }
  }

  // ---- noise z[9] (pure ALU, after prefetch registers are dead) ----
  unsigned base = 9u * (unsigned)v;
  float z[9];
#pragma unroll
  for (int e = 0; e < 9; ++e) z[e] = jax_normal_at(base + (unsigned)e);

  // ---- tensor (LT_INDICES): [[f0,f1,f3],[f1,f2,f4],[f3,f4,f5]] + noise, symmetrized ----
  const float eps = 1e-6f;
  float a00 = f0 + eps * z[0];
  float a11 = f2 + eps * z[4];
  float a22 = f5 + eps * z[8];
  float a01 = ((f1 + eps * z[1]) + (f1 + eps * z[3])) * 0.5f;
  float a02 = ((f3 + eps * z[2]) + (f3 + eps * z[6])) * 0.5f;
  float a12 = ((f4 + eps * z[5]) + (f4 + eps * z[7])) * 0.5f;

  // ---- closed-form symmetric 3x3 eigenvalues (trigonometric method) ----
  float q = (a00 + a11 + a22) * (1.0f / 3.0f);
  float aa = a00 - q, bb = a11 - q, cc = a22 - q;
  float p2 = aa * aa + bb * bb + cc * cc +
             2.0f * (a01 * a01 + a02 * a02 + a12 * a12);
  float pp = __builtin_sqrtf(p2 * (1.0f / 6.0f));
  float invp = (pp > 0.0f) ? (1.0f / pp) : 0.0f;
  float b00 = aa * invp, b11 = bb * invp, b22 = cc * invp;
  float b01 = a01 * invp, b02 = a02 * invp, b12 = a12 * invp;
  float detB = b00 * (b11 * b22 - b12 * b12)
             - b01 * (b01 * b22 - b12 * b02)
             + b02 * (b01 * b12 - b11 * b02);
  float r = 0.5f * detB;
  r = fminf(1.0f, fmaxf(-1.0f, r));
  float phi = acosf(r) * (1.0f / 3.0f);
  float l0 = q + 2.0f * pp * cosf(phi);
  float l2 = q + 2.0f * pp * cosf(phi + 2.0943951023931953f); // +2pi/3
  float l1 = 3.0f * q - l0 - l2;

  // ---- clamp, FA ----
  l0 = fmaxf(l0, md);
  l1 = fmaxf(l1, md);
  l2 = fmaxf(l2, md);
  float d01 = l0 - l1, d12 = l1 - l2, d20 = l2 - l0;
  float num = 0.5f * (d01 * d01 + d12 * d12 + d20 * d20);
  float den = l0 * l0 + l1 * l1 + l2 * l2;  // >= 3*md^2 > 0
  float fa = __builtin_sqrtf(num / den);

  if (v < nvox) out[v] = fa * mv;
}

extern "C" void kernel_launch(void* const* d_in, const int* in_sizes, int n_in,
                              void* d_out, int out_size, void* d_ws, size_t ws_size,
                              hipStream_t stream) {
  const float* dwi  = (const float*)d_in[0];
  const float* mask = (const float*)d_in[1];
  const float* W    = (const float*)d_in[2];
  const float* mdp  = (const float*)d_in[3];
  float* out = (float*)d_out;
  int nvox = in_sizes[0] / NG;  // 1,000,000
  int grid = (nvox + 255) / 256;
  hipLaunchKernelGGL(fa_kernel, dim3(grid), dim3(256), 0, stream,
                     dwi, mask, W, mdp, out, nvox);
}